// Round 5
// baseline (467.889 us; speedup 1.0000x reference)
//
#include <hip/hip_runtime.h>

// Problem constants (reference: B,S,M,D,NQ = 128,100,50,128,10000)
#define BB 128
#define SS 100
#define MM 50
#define DD 128
#define KSTR 136   // key LDS row stride (f32 words): 136 % 32 == 8 -> 2-way (free) bank aliasing

// ---- helpers ----
__device__ __forceinline__ float bf2f(unsigned short u) {
    union { unsigned int i; float f; } c; c.i = ((unsigned int)u) << 16; return c.f;
}
__device__ __forceinline__ unsigned short f2bf_bits(float f) {   // round-to-nearest-even
    union { float f; unsigned int u; } c; c.f = f;
    unsigned int r = (c.u + 0x7FFFu + ((c.u >> 16) & 1u)) >> 16;
    return (unsigned short)r;
}
__device__ __forceinline__ float fast_sigmoid(float x) { return 1.0f / (1.0f + __expf(-x)); }
__device__ __forceinline__ float fast_tanh(float x) {
    float ax = fabsf(x);
    float z = __expf(-2.0f * ax);
    float r = (1.0f - z) / (1.0f + z);
    return copysignf(r, x);
}

// dtype-generic element load: BF16 ? bf16[idx] : f32[idx]
template <bool BF16>
__device__ __forceinline__ float ldw(const void* p, size_t idx) {
    if (BF16) return bf2f(((const unsigned short*)p)[idx]);
    return ((const float*)p)[idx];
}

struct SmemT {
    float key_f[MM][KSTR];
    float qe[DD];
    float logit[64];
    float wrow[52];
    float read_f[DD];
    float h_f[DD];
    float up_f[DD];
    float fscr[DD];
    float h1f[DD];
};

// 512 threads: lane l = t&63; d = (t>>6)*16 + (l&15) in [0,128); q = l>>4 covers k in [32q,32q+32).
// v[m][d] for m = q+4j in registers. All five weight quarter-columns in registers (f32).
template <bool BF16>
__device__ void dkvmn_impl(
    const int* __restrict__ qseq,
    const void* emb, const void* key,
    const void* vu_w1, const void* vu_b1, const void* vu_w2, const void* vu_b2,
    const void* er_w, const void* er_b, const void* ad_w, const void* ad_b,
    const void* out_w1, const void* out_b1, const void* out_w2, const void* out_b2,
    void* outp, SmemT& sm)
{
    const int t = threadIdx.x;
    const int b = blockIdx.x;
    const int l = t & 63;
    const int d = ((t >> 6) << 4) + (l & 15);
    const int q = l >> 4;

    // stage key matrix (50x128) into LDS as f32
    for (int idx = t; idx < MM * DD; idx += 512)
        sm.key_f[idx >> 7][idx & 127] = ldw<BF16>(key, idx);

    // register weights: quarter-columns for output column d, k in [32q, 32q+32)
    float rw1a[32], rw1b[32], rw2[32], rer[32], rad[32];
#pragma unroll
    for (int i = 0; i < 32; ++i) {
        int k = 32 * q + i;
        rw1a[i] = ldw<BF16>(vu_w1, (size_t)k * DD + d);
        rw1b[i] = ldw<BF16>(vu_w1, (size_t)(DD + k) * DD + d);
        rw2[i]  = ldw<BF16>(vu_w2, (size_t)k * DD + d);
        rer[i]  = ldw<BF16>(er_w,  (size_t)k * DD + d);
        rad[i]  = ldw<BF16>(ad_w,  (size_t)k * DD + d);
    }

    float v[13];
#pragma unroll
    for (int j = 0; j < 13; ++j) v[j] = 0.f;

    const float b1r = ldw<BF16>(vu_b1, d);
    const float b2r = ldw<BF16>(vu_b2, d);
    const float ebr = ldw<BF16>(er_b, d);
    const float abr = ldw<BF16>(ad_b, d);

    const int* qrow = qseq + b * SS;

    __syncthreads();   // key_f ready

    for (int s = 0; s < SS; ++s) {
        // A: load qe
        if (t < DD) sm.qe[t] = ldw<BF16>(emb, (size_t)qrow[s] * DD + t);
        __syncthreads();

        // B: logits (m = t>>3, k8 = t&7, k = k8 + 8i) and qe-projection qp
        {
            int m = t >> 3, k8 = t & 7;
            float acc = 0.f;
            if (m < MM) {
#pragma unroll
                for (int i = 0; i < 16; ++i)
                    acc = fmaf(sm.key_f[m][k8 + 8 * i], sm.qe[k8 + 8 * i], acc);
            }
            acc += __shfl_xor(acc, 1);
            acc += __shfl_xor(acc, 2);
            acc += __shfl_xor(acc, 4);
            if (k8 == 0 && m < MM) sm.logit[m] = acc;
        }
        float qp = 0.f;
#pragma unroll
        for (int i = 0; i < 32; ++i) qp = fmaf(rw1b[i], sm.qe[32 * q + i], qp);
        qp += __shfl_xor(qp, 16);
        qp += __shfl_xor(qp, 32);
        __syncthreads();   // logit ready

        // C: softmax over M=50 by wave 0
        if (t < 64) {
            float x = (t < MM) ? sm.logit[t] : -1e30f;
            float mx = x;
#pragma unroll
            for (int o = 32; o > 0; o >>= 1) mx = fmaxf(mx, __shfl_xor(mx, o));
            float p = (t < MM) ? __expf(x - mx) : 0.f;
            float s2 = p;
#pragma unroll
            for (int o = 32; o > 0; o >>= 1) s2 += __shfl_xor(s2, o);
            if (t < MM) sm.wrow[t] = p / s2;
        }
        __syncthreads();   // wrow ready

        // D: read[d] = sum_m wrow[m] v[m][d]
        float r = 0.f;
#pragma unroll
        for (int j = 0; j < 12; ++j) r = fmaf(sm.wrow[q + 4 * j], v[j], r);
        if (q < 2) r = fmaf(sm.wrow[q + 48], v[12], r);
        r += __shfl_xor(r, 16);
        r += __shfl_xor(r, 32);
        if (q == 0) sm.read_f[d] = r;
        __syncthreads();

        // E: h = tanh(read @ w1a + qp + b1)
        float acc = 0.f;
#pragma unroll
        for (int i = 0; i < 32; ++i) acc = fmaf(rw1a[i], sm.read_f[32 * q + i], acc);
        acc += __shfl_xor(acc, 16);
        acc += __shfl_xor(acc, 32);
        float hh = fast_tanh(acc + qp + b1r);
        if (q == 0) sm.h_f[d] = hh;
        __syncthreads();

        // F: up = h @ w2 + b2
        acc = 0.f;
#pragma unroll
        for (int i = 0; i < 32; ++i) acc = fmaf(rw2[i], sm.h_f[32 * q + i], acc);
        acc += __shfl_xor(acc, 16);
        acc += __shfl_xor(acc, 32);
        float up = acc + b2r;
        if (q == 0) sm.up_f[d] = up;
        __syncthreads();

        // G: e = sigmoid(up@er+eb), a = tanh(up@ad+ab); v update
        float ae = 0.f, aa = 0.f;
#pragma unroll
        for (int i = 0; i < 32; ++i) {
            float x0 = sm.up_f[32 * q + i];
            ae = fmaf(rer[i], x0, ae);
            aa = fmaf(rad[i], x0, aa);
        }
        ae += __shfl_xor(ae, 16); ae += __shfl_xor(ae, 32);
        aa += __shfl_xor(aa, 16); aa += __shfl_xor(aa, 32);
        float e = fast_sigmoid(ae + ebr);
        float a = fast_tanh(aa + abr);
#pragma unroll
        for (int j = 0; j < 12; ++j) {
            float wm = sm.wrow[q + 4 * j];
            v[j] = fmaf(v[j], fmaf(-wm, e, 1.0f), wm * a);
        }
        if (q < 2) {
            float wm = sm.wrow[q + 48];
            v[12] = fmaf(v[12], fmaf(-wm, e, 1.0f), wm * a);
        }
        // no barrier needed: next A writes only qe, which G does not read;
        // wrow/up_f are rewritten only after >=2 intervening barriers.
    }

    // Epilogue: final read (wrow holds s=99; qe holds last qe)
    float r = 0.f;
#pragma unroll
    for (int j = 0; j < 12; ++j) r = fmaf(sm.wrow[q + 4 * j], v[j], r);
    if (q < 2) r = fmaf(sm.wrow[q + 48], v[12], r);
    r += __shfl_xor(r, 16);
    r += __shfl_xor(r, 32);
    if (q == 0) sm.fscr[d] = r;
    __syncthreads();

    // h1 = relu([read, last_qe] @ out_w1 + out_b1); thread covers k in [64q, 64q+64)
    float acc = 0.f;
    for (int i = 0; i < 64; ++i) {
        int k = 64 * q + i;
        float x = (k < DD) ? sm.fscr[k] : sm.qe[k - DD];
        acc = fmaf(ldw<BF16>(out_w1, (size_t)k * DD + d), x, acc);
    }
    acc += __shfl_xor(acc, 16);
    acc += __shfl_xor(acc, 32);
    float h1 = fmaxf(acc + ldw<BF16>(out_b1, d), 0.f);
    if (q == 0) sm.h1f[d] = h1;
    __syncthreads();

    if (t < 64) {
        float xs = fmaf(sm.h1f[t], ldw<BF16>(out_w2, t),
                        sm.h1f[64 + t] * ldw<BF16>(out_w2, 64 + t));
#pragma unroll
        for (int o = 32; o > 0; o >>= 1) xs += __shfl_xor(xs, o);
        if (t == 0) {
            float pred = fast_sigmoid(xs + ldw<BF16>(out_b2, 0));
            if (BF16) ((unsigned short*)outp)[b] = f2bf_bits(pred);
            else      ((float*)outp)[b] = pred;
        }
    }
}

__global__ __launch_bounds__(512) void DKVMN_78546361909953_kernel(
    const int* __restrict__ qseq,
    const void* emb, const void* key,
    const void* vu_w1, const void* vu_b1, const void* vu_w2, const void* vu_b2,
    const void* er_w, const void* er_b, const void* ad_w, const void* ad_b,
    const void* out_w1, const void* out_b1, const void* out_w2, const void* out_b2,
    void* outp)
{
    __shared__ SmemT sm;

    // Runtime storage-dtype detection (wave-uniform): low 16 bits of the first 32
    // u32 words of emb. bf16 storage -> low halves are bf16 numbers, exponent field
    // in [100,127] for xavier-scale data (~32/32 hits). f32 storage -> low halves
    // are uniform mantissa bits (~3/32 hits). Threshold 16.
    const unsigned int* eu = (const unsigned int*)emb;
    int cnt = 0;
    for (int i = 0; i < 32; ++i) {
        unsigned int e8 = (eu[i] >> 7) & 0xFFu;
        cnt += (e8 >= 100u && e8 <= 127u) ? 1 : 0;
    }
    if (cnt >= 16)
        dkvmn_impl<true>(qseq, emb, key, vu_w1, vu_b1, vu_w2, vu_b2,
                         er_w, er_b, ad_w, ad_b, out_w1, out_b1, out_w2, out_b2, outp, sm);
    else
        dkvmn_impl<false>(qseq, emb, key, vu_w1, vu_b1, vu_w2, vu_b2,
                          er_w, er_b, ad_w, ad_b, out_w1, out_b1, out_w2, out_b2, outp, sm);
}

extern "C" void kernel_launch(void* const* d_in, const int* in_sizes, int n_in,
                              void* d_out, int out_size, void* d_ws, size_t ws_size,
                              hipStream_t stream) {
    const int* qseq = (const int*)d_in[0];
    // d_in[1] = answer_seq: unused by the reference
    DKVMN_78546361909953_kernel<<<BB, 512, 0, stream>>>(
        qseq,
        d_in[2], d_in[3], d_in[4], d_in[5], d_in[6], d_in[7],
        d_in[8], d_in[9], d_in[10], d_in[11],
        d_in[12], d_in[13], d_in[14], d_in[15],
        d_out);
}

// Round 6
// 335.891 us; speedup vs baseline: 1.3930x; 1.3930x over previous
//
#include <hip/hip_runtime.h>

// Problem constants (reference: B,S,M,D,NQ = 128,100,50,128,10000)
#define BB 128
#define SS 100
#define MM 50
#define DD 128
#define KROW 34            // key LDS row stride in u32 words (= 68 bf16): low bank aliasing
#define XW(k) ((k) + 8 * ((k) >> 5))   // strided x-buffer: q-slices land on disjoint banks
#define XBUF 152

// ---- bf16 helpers (pure integer bit ops) ----
__device__ __forceinline__ float bf2f(unsigned short u) {
    union { unsigned int i; float f; } c; c.i = ((unsigned int)u) << 16; return c.f;
}
__device__ __forceinline__ float bfu_lo(unsigned int u) {
    union { unsigned int i; float f; } c; c.i = u << 16; return c.f;
}
__device__ __forceinline__ float bfu_hi(unsigned int u) {
    union { unsigned int i; float f; } c; c.i = u & 0xffff0000u; return c.f;
}
__device__ __forceinline__ unsigned short f2bf_bits(float f) {   // RNE
    union { float f; unsigned int u; } c; c.f = f;
    unsigned int r = (c.u + 0x7FFFu + ((c.u >> 16) & 1u)) >> 16;
    return (unsigned short)r;
}
__device__ __forceinline__ unsigned int packbf(float lo, float hi) {
    return (unsigned int)f2bf_bits(lo) | ((unsigned int)f2bf_bits(hi) << 16);
}
__device__ __forceinline__ float fast_sigmoid(float x) { return 1.0f / (1.0f + __expf(-x)); }
__device__ __forceinline__ float fast_tanh(float x) {
    float ax = fabsf(x);
    float z = __expf(-2.0f * ax);
    float r = (1.0f - z) / (1.0f + z);
    return copysignf(r, x);
}

template <bool BF16>
__device__ __forceinline__ float ldw(const void* p, size_t idx) {
    if (BF16) return bf2f(((const unsigned short*)p)[idx]);
    return ((const float*)p)[idx];
}
template <bool BF16>
__device__ __forceinline__ unsigned int load_qe_word(const void* emb, int row, int tt) {
    if (BF16) return ((const unsigned int*)emb)[((size_t)row << 6) + tt];
    const float* ef = (const float*)emb + (((size_t)row) << 7) + 2 * tt;
    return packbf(ef[0], ef[1]);
}

struct __align__(16) SmemT {
    unsigned int key_w[MM * KROW];   // key as packed bf16 pairs, 34-word rows
    unsigned int qe_w[64];           // current qe, packed bf16
    int   qrow[SS];
    float logit[64];
    float wrow[64];                  // padded; [50..64) written 0 by softmax
    float xread[XBUF];
    float xh[XBUF];
    float xup[XBUF];
    float h1f[DD];
};

// 512 threads: wave wv = t>>6, lane l = t&63; d = 16*wv + (l&15); q = l>>4 (k-quarter).
// v[m][d] for m = 16q+j (j<16; m>=50 inert via wrow==0). Weights in f32 registers.
template <bool BF16>
__device__ void dkvmn_impl(
    const int* __restrict__ qseq,
    const void* emb, const void* key,
    const void* vu_w1, const void* vu_b1, const void* vu_w2, const void* vu_b2,
    const void* er_w, const void* er_b, const void* ad_w, const void* ad_b,
    const void* out_w1, const void* out_b1, const void* out_w2, const void* out_b2,
    void* outp, SmemT& sm)
{
    const int t = threadIdx.x;
    const int b = blockIdx.x;
    const int l = t & 63;
    const int d = ((t >> 6) << 4) + (l & 15);
    const int q = l >> 4;

    // ---- stage key (bf16-packed) + qrow ----
    if (BF16) {
        const unsigned int* kg = (const unsigned int*)key;
        for (int g = t; g < MM * 64; g += 512)
            sm.key_w[(g >> 6) * KROW + (g & 63)] = kg[g];
    } else {
        const float* kf = (const float*)key;
        for (int g = t; g < MM * 64; g += 512) {
            int row = g >> 6, c2 = g & 63;
            sm.key_w[row * KROW + c2] = packbf(kf[row * 128 + 2 * c2], kf[row * 128 + 2 * c2 + 1]);
        }
    }
    for (int g = t; g < SS; g += 512) sm.qrow[g] = qseq[b * SS + g];

    // ---- weights into registers (f32), k in [32q, 32q+32) for column d ----
    float rw1a[32], rw1b[32], rw2[32], rer[32], rad[32];
#pragma unroll
    for (int i = 0; i < 32; ++i) {
        int k = 32 * q + i;
        rw1a[i] = ldw<BF16>(vu_w1, (size_t)k * DD + d);
        rw1b[i] = ldw<BF16>(vu_w1, (size_t)(DD + k) * DD + d);
        rw2[i]  = ldw<BF16>(vu_w2, (size_t)k * DD + d);
        rer[i]  = ldw<BF16>(er_w,  (size_t)k * DD + d);
        rad[i]  = ldw<BF16>(ad_w,  (size_t)k * DD + d);
    }
    const float b1r = ldw<BF16>(vu_b1, d);
    const float b2r = ldw<BF16>(vu_b2, d);
    const float ebr = ldw<BF16>(er_b, d);
    const float abr = ldw<BF16>(ad_b, d);

    float v[16];
#pragma unroll
    for (int j = 0; j < 16; ++j) v[j] = 0.f;
    float wrowr[16];

    __syncthreads();   // key/qrow ready

    if (t < 64) sm.qe_w[t] = load_qe_word<BF16>(emb, sm.qrow[0], t);
    __syncthreads();

    unsigned int qnext_u = 0;
    float2 qnext_f = {0.f, 0.f};

    for (int s = 0; s < SS; ++s) {
        // ---- B: logits (threads (m,k8)) + qe-projection qp (threads (d,q)) ----
        {
            int m8 = t >> 3, k8 = t & 7;
            if (m8 < 56) {   // wave-uniform: waves 0..6 enter, wave 7 skips
                int mc = (m8 < MM) ? m8 : (MM - 1);
                const uint2* kp = (const uint2*)&sm.key_w[mc * KROW + 8 * k8];
                uint2 kw0 = kp[0], kw1 = kp[1], kw2 = kp[2], kw3 = kp[3];
                const uint4* qp4 = (const uint4*)&sm.qe_w[8 * k8];
                uint4 qa = qp4[0], qb = qp4[1];
                float s0 = 0.f, s1 = 0.f;
                s0 = fmaf(bfu_lo(kw0.x), bfu_lo(qa.x), s0); s1 = fmaf(bfu_hi(kw0.x), bfu_hi(qa.x), s1);
                s0 = fmaf(bfu_lo(kw0.y), bfu_lo(qa.y), s0); s1 = fmaf(bfu_hi(kw0.y), bfu_hi(qa.y), s1);
                s0 = fmaf(bfu_lo(kw1.x), bfu_lo(qa.z), s0); s1 = fmaf(bfu_hi(kw1.x), bfu_hi(qa.z), s1);
                s0 = fmaf(bfu_lo(kw1.y), bfu_lo(qa.w), s0); s1 = fmaf(bfu_hi(kw1.y), bfu_hi(qa.w), s1);
                s0 = fmaf(bfu_lo(kw2.x), bfu_lo(qb.x), s0); s1 = fmaf(bfu_hi(kw2.x), bfu_hi(qb.x), s1);
                s0 = fmaf(bfu_lo(kw2.y), bfu_lo(qb.y), s0); s1 = fmaf(bfu_hi(kw2.y), bfu_hi(qb.y), s1);
                s0 = fmaf(bfu_lo(kw3.x), bfu_lo(qb.z), s0); s1 = fmaf(bfu_hi(kw3.x), bfu_hi(qb.z), s1);
                s0 = fmaf(bfu_lo(kw3.y), bfu_lo(qb.w), s0); s1 = fmaf(bfu_hi(kw3.y), bfu_hi(qb.w), s1);
                float acc = s0 + s1;
                acc += __shfl_xor(acc, 1);
                acc += __shfl_xor(acc, 2);
                acc += __shfl_xor(acc, 4);
                if (k8 == 0 && m8 < MM) sm.logit[m8] = acc;
            }
        }
        float qp;
        {
            const uint4* qq = (const uint4*)&sm.qe_w[16 * q];
            uint4 x0 = qq[0], x1 = qq[1], x2 = qq[2], x3 = qq[3];
            unsigned int qa[16] = { x0.x, x0.y, x0.z, x0.w, x1.x, x1.y, x1.z, x1.w,
                                    x2.x, x2.y, x2.z, x2.w, x3.x, x3.y, x3.z, x3.w };
            float p0 = 0.f, p1 = 0.f;
#pragma unroll
            for (int i = 0; i < 16; ++i) {
                p0 = fmaf(rw1b[2 * i],     bfu_lo(qa[i]), p0);
                p1 = fmaf(rw1b[2 * i + 1], bfu_hi(qa[i]), p1);
            }
            qp = p0 + p1;
            qp += __shfl_xor(qp, 16);
            qp += __shfl_xor(qp, 32);
        }
        __syncthreads();   // logit ready

        // ---- C: softmax over M=50 (wave 0); writes zeros for m>=50 ----
        if (t < 64) {
            float x = (t < MM) ? sm.logit[t] : -1e30f;
            float mx = x;
#pragma unroll
            for (int o = 32; o > 0; o >>= 1) mx = fmaxf(mx, __shfl_xor(mx, o));
            float p = (t < MM) ? __expf(x - mx) : 0.f;
            float sum = p;
#pragma unroll
            for (int o = 32; o > 0; o >>= 1) sum += __shfl_xor(sum, o);
            sm.wrow[t] = p / sum;
        }
        __syncthreads();   // wrow ready

        // ---- D: wrow -> regs; read[d] = sum_m w[m] v[m][d]; prefetch next qe ----
        {
            const float4* wp = (const float4*)&sm.wrow[16 * q];
            float4 w0 = wp[0], w1 = wp[1], w2_ = wp[2], w3 = wp[3];
            wrowr[0] = w0.x;  wrowr[1] = w0.y;  wrowr[2] = w0.z;  wrowr[3] = w0.w;
            wrowr[4] = w1.x;  wrowr[5] = w1.y;  wrowr[6] = w1.z;  wrowr[7] = w1.w;
            wrowr[8] = w2_.x; wrowr[9] = w2_.y; wrowr[10] = w2_.z; wrowr[11] = w2_.w;
            wrowr[12] = w3.x; wrowr[13] = w3.y; wrowr[14] = w3.z; wrowr[15] = w3.w;
        }
        {
            float r0 = 0.f, r1 = 0.f;
#pragma unroll
            for (int j = 0; j < 16; j += 2) {
                r0 = fmaf(wrowr[j], v[j], r0);
                r1 = fmaf(wrowr[j + 1], v[j + 1], r1);
            }
            float r = r0 + r1;
            r += __shfl_xor(r, 16);
            r += __shfl_xor(r, 32);
            if (q == 0) sm.xread[XW(d)] = r;
        }
        if (s + 1 < SS && t < 64) {
            int nr = sm.qrow[s + 1];
            if (BF16) qnext_u = ((const unsigned int*)emb)[((size_t)nr << 6) + t];
            else      qnext_f = *(const float2*)((const float*)emb + (((size_t)nr) << 7) + 2 * t);
        }
        __syncthreads();   // xread ready

        // ---- E: h = tanh(read @ w1a + qp + b1) ----
        {
            const float4* xp = (const float4*)&sm.xread[40 * q];
            float a0 = 0.f, a1 = 0.f, a2 = 0.f, a3 = 0.f;
#pragma unroll
            for (int j = 0; j < 8; ++j) {
                float4 xv = xp[j];
                a0 = fmaf(rw1a[4 * j],     xv.x, a0);
                a1 = fmaf(rw1a[4 * j + 1], xv.y, a1);
                a2 = fmaf(rw1a[4 * j + 2], xv.z, a2);
                a3 = fmaf(rw1a[4 * j + 3], xv.w, a3);
            }
            float acc = (a0 + a1) + (a2 + a3);
            acc += __shfl_xor(acc, 16);
            acc += __shfl_xor(acc, 32);
            float hh = fast_tanh(acc + qp + b1r);
            if (q == 0) sm.xh[XW(d)] = hh;
        }
        __syncthreads();   // xh ready

        // ---- F: up = h @ w2 + b2 ----
        {
            const float4* xp = (const float4*)&sm.xh[40 * q];
            float a0 = 0.f, a1 = 0.f, a2 = 0.f, a3 = 0.f;
#pragma unroll
            for (int j = 0; j < 8; ++j) {
                float4 xv = xp[j];
                a0 = fmaf(rw2[4 * j],     xv.x, a0);
                a1 = fmaf(rw2[4 * j + 1], xv.y, a1);
                a2 = fmaf(rw2[4 * j + 2], xv.z, a2);
                a3 = fmaf(rw2[4 * j + 3], xv.w, a3);
            }
            float acc = (a0 + a1) + (a2 + a3);
            acc += __shfl_xor(acc, 16);
            acc += __shfl_xor(acc, 32);
            float up = acc + b2r;
            if (q == 0) sm.xup[XW(d)] = up;
        }
        __syncthreads();   // xup ready

        // ---- G: e/a; v update; publish prefetched qe ----
        {
            const float4* xp = (const float4*)&sm.xup[40 * q];
            float e0 = 0.f, e1 = 0.f, f0 = 0.f, f1 = 0.f;
#pragma unroll
            for (int j = 0; j < 8; ++j) {
                float4 xv = xp[j];
                e0 = fmaf(rer[4 * j],     xv.x, e0); e1 = fmaf(rer[4 * j + 1], xv.y, e1);
                e0 = fmaf(rer[4 * j + 2], xv.z, e0); e1 = fmaf(rer[4 * j + 3], xv.w, e1);
                f0 = fmaf(rad[4 * j],     xv.x, f0); f1 = fmaf(rad[4 * j + 1], xv.y, f1);
                f0 = fmaf(rad[4 * j + 2], xv.z, f0); f1 = fmaf(rad[4 * j + 3], xv.w, f1);
            }
            float ae = e0 + e1, aa = f0 + f1;
            ae += __shfl_xor(ae, 16); ae += __shfl_xor(ae, 32);
            aa += __shfl_xor(aa, 16); aa += __shfl_xor(aa, 32);
            float e = fast_sigmoid(ae + ebr);
            float a = fast_tanh(aa + abr);
#pragma unroll
            for (int j = 0; j < 16; ++j) {
                float wm = wrowr[j];
                v[j] = fmaf(v[j], fmaf(-wm, e, 1.0f), wm * a);
            }
        }
        if (s + 1 < SS && t < 64) {
            if (BF16) sm.qe_w[t] = qnext_u;
            else      sm.qe_w[t] = packbf(qnext_f.x, qnext_f.y);
        }
        __syncthreads();   // qe ready for next B; xup reads done
    }

    // ---- Epilogue: final read (wrowr/v hold s=99), output head ----
    {
        float r0 = 0.f, r1 = 0.f;
#pragma unroll
        for (int j = 0; j < 16; j += 2) {
            r0 = fmaf(wrowr[j], v[j], r0);
            r1 = fmaf(wrowr[j + 1], v[j + 1], r1);
        }
        float r = r0 + r1;
        r += __shfl_xor(r, 16);
        r += __shfl_xor(r, 32);
        if (q == 0) sm.xread[XW(d)] = r;
    }
    __syncthreads();

    // h1[d] = relu([read, last_qe] @ out_w1 + b); thread covers k in [64q, 64q+64)
    float acc = 0.f;
    if (q < 2) {
#pragma unroll
        for (int sl = 0; sl < 2; ++sl) {
            int sidx = 2 * q + sl;
            const float4* xp = (const float4*)&sm.xread[40 * sidx];
#pragma unroll
            for (int j = 0; j < 8; ++j) {
                float4 xv = xp[j];
                int k = 32 * sidx + 4 * j;
                acc = fmaf(ldw<BF16>(out_w1, (size_t)k * DD + d),       xv.x, acc);
                acc = fmaf(ldw<BF16>(out_w1, (size_t)(k + 1) * DD + d), xv.y, acc);
                acc = fmaf(ldw<BF16>(out_w1, (size_t)(k + 2) * DD + d), xv.z, acc);
                acc = fmaf(ldw<BF16>(out_w1, (size_t)(k + 3) * DD + d), xv.w, acc);
            }
        }
    } else {
        int half = q - 2;
#pragma unroll
        for (int i = 0; i < 32; ++i) {
            unsigned int u = sm.qe_w[32 * half + i];
            int k = DD + 64 * half + 2 * i;
            acc = fmaf(ldw<BF16>(out_w1, (size_t)k * DD + d),       bfu_lo(u), acc);
            acc = fmaf(ldw<BF16>(out_w1, (size_t)(k + 1) * DD + d), bfu_hi(u), acc);
        }
    }
    acc += __shfl_xor(acc, 16);
    acc += __shfl_xor(acc, 32);
    float h1 = fmaxf(acc + ldw<BF16>(out_b1, d), 0.f);
    if (q == 0) sm.h1f[d] = h1;
    __syncthreads();

    if (t < 64) {
        float xs = fmaf(sm.h1f[t], ldw<BF16>(out_w2, t),
                        sm.h1f[64 + t] * ldw<BF16>(out_w2, 64 + t));
#pragma unroll
        for (int o = 32; o > 0; o >>= 1) xs += __shfl_xor(xs, o);
        if (t == 0) {
            float pred = fast_sigmoid(xs + ldw<BF16>(out_b2, 0));
            if (BF16) ((unsigned short*)outp)[b] = f2bf_bits(pred);
            else      ((float*)outp)[b] = pred;
        }
    }
}

__global__ __launch_bounds__(512) void DKVMN_78546361909953_kernel(
    const int* __restrict__ qseq,
    const void* emb, const void* key,
    const void* vu_w1, const void* vu_b1, const void* vu_w2, const void* vu_b2,
    const void* er_w, const void* er_b, const void* ad_w, const void* ad_b,
    const void* out_w1, const void* out_b1, const void* out_w2, const void* out_b2,
    void* outp)
{
    __shared__ SmemT sm;

    // Runtime storage-dtype detection (proven in round 5): bf16 low-halves have
    // exponent bits in [100,127] for xavier-scale data; f32 low-halves are mantissa noise.
    const unsigned int* eu = (const unsigned int*)emb;
    int cnt = 0;
    for (int i = 0; i < 32; ++i) {
        unsigned int e8 = (eu[i] >> 7) & 0xFFu;
        cnt += (e8 >= 100u && e8 <= 127u) ? 1 : 0;
    }
    if (cnt >= 16)
        dkvmn_impl<true>(qseq, emb, key, vu_w1, vu_b1, vu_w2, vu_b2,
                         er_w, er_b, ad_w, ad_b, out_w1, out_b1, out_w2, out_b2, outp, sm);
    else
        dkvmn_impl<false>(qseq, emb, key, vu_w1, vu_b1, vu_w2, vu_b2,
                          er_w, er_b, ad_w, ad_b, out_w1, out_b1, out_w2, out_b2, outp, sm);
}

extern "C" void kernel_launch(void* const* d_in, const int* in_sizes, int n_in,
                              void* d_out, int out_size, void* d_ws, size_t ws_size,
                              hipStream_t stream) {
    const int* qseq = (const int*)d_in[0];
    // d_in[1] = answer_seq: unused by the reference
    DKVMN_78546361909953_kernel<<<BB, 512, 0, stream>>>(
        qseq,
        d_in[2], d_in[3], d_in[4], d_in[5], d_in[6], d_in[7],
        d_in[8], d_in[9], d_in[10], d_in[11],
        d_in[12], d_in[13], d_in[14], d_in[15],
        d_out);
}

// Round 8
// 284.973 us; speedup vs baseline: 1.6419x; 1.1787x over previous
//
#include <hip/hip_runtime.h>

// Problem constants (reference: B,S,M,D,NQ = 128,100,50,128,10000)
#define BB 128
#define SS 100
#define MM 50
#define DD 128
#define KROW 66            // key row stride in u32 words: >=64 (NO row overlap; r7 bug) + 2 pad
#define XW(k) ((k) + 8 * ((k) >> 5))   // strided x-buffer: q-slices land on disjoint banks
#define XBUF 152

// ---- bf16 helpers (pure integer bit ops) ----
__device__ __forceinline__ float bf2f(unsigned short u) {
    union { unsigned int i; float f; } c; c.i = ((unsigned int)u) << 16; return c.f;
}
__device__ __forceinline__ float bfu_lo(unsigned int u) {
    union { unsigned int i; float f; } c; c.i = u << 16; return c.f;
}
__device__ __forceinline__ float bfu_hi(unsigned int u) {
    union { unsigned int i; float f; } c; c.i = u & 0xffff0000u; return c.f;
}
__device__ __forceinline__ unsigned short f2bf_bits(float f) {   // RNE
    union { float f; unsigned int u; } c; c.f = f;
    unsigned int r = (c.u + 0x7FFFu + ((c.u >> 16) & 1u)) >> 16;
    return (unsigned short)r;
}
__device__ __forceinline__ unsigned int packbf(float lo, float hi) {
    return (unsigned int)f2bf_bits(lo) | ((unsigned int)f2bf_bits(hi) << 16);
}
__device__ __forceinline__ float fast_sigmoid(float x) { return 1.0f / (1.0f + __expf(-x)); }
__device__ __forceinline__ float fast_tanh(float x) {
    float ax = fabsf(x);
    float z = __expf(-2.0f * ax);
    float r = (1.0f - z) / (1.0f + z);
    return copysignf(r, x);
}

template <bool BF16>
__device__ __forceinline__ float ldw(const void* p, size_t idx) {
    if (BF16) return bf2f(((const unsigned short*)p)[idx]);
    return ((const float*)p)[idx];
}

struct __align__(16) SmemT {
    union {
        struct {                         // precompute phase
            unsigned int key_w[MM * KROW];   // 13200 B, packed bf16 pairs, stride 66 (no overlap)
            unsigned int qe8[8][68];         // 2176 B, 8 staged qe rows, packed bf16
        } pre;                           // 15376 B
        struct {                         // scan phase (fits inside key_w region)
            float xread[XBUF];
            float xh[XBUF];
            float xup[XBUF];
            float h1f[DD];
        } run;                           // 2336 B
    } u;
    unsigned int wrow_p[SS][32];         // 12800 B, packed bf16 attention rows (m>=50 zero)
    unsigned short qp_all[SS][DD];       // 25600 B, bf16 qe-projections
    int qrow[SS];                        // 400 B
    float qlast[DD];                     // 512 B
};                                       // total 54688 B < 64 KB

// 512 threads: wave wv = t>>6, lane l = t&63; d = 16*wv + (l&15); q = l>>4 (k-quarter).
// v[m][d] for m = 16q+j (m>=50 inert: wrow==0). Weights in f32 registers.
template <bool BF16>
__device__ void dkvmn_impl(
    const int* __restrict__ qseq,
    const void* emb, const void* key,
    const void* vu_w1, const void* vu_b1, const void* vu_w2, const void* vu_b2,
    const void* er_w, const void* er_b, const void* ad_w, const void* ad_b,
    const void* out_w1, const void* out_b1, const void* out_w2, const void* out_b2,
    void* outp, SmemT& sm)
{
    const int t = threadIdx.x;
    const int b = blockIdx.x;
    const int l = t & 63;
    const int wv = t >> 6;
    const int d = (wv << 4) + (l & 15);
    const int q = l >> 4;

    // ---- stage key (packed bf16, stride 66: row m occupies [66m, 66m+64), in bounds) ----
    if (BF16) {
        const unsigned int* kg = (const unsigned int*)key;
        for (int g = t; g < MM * 64; g += 512)
            sm.u.pre.key_w[(g >> 6) * KROW + (g & 63)] = kg[g];
    } else {
        const float* kf = (const float*)key;
        for (int g = t; g < MM * 64; g += 512) {
            int row = g >> 6, c2 = g & 63;
            sm.u.pre.key_w[row * KROW + c2] = packbf(kf[row * 128 + 2 * c2], kf[row * 128 + 2 * c2 + 1]);
        }
    }
    for (int g = t; g < SS; g += 512) sm.qrow[g] = qseq[b * SS + g];

    // ---- weights into registers (f32), k in [32q, 32q+32) for column d ----
    float rw1a[32], rw1b[32], rw2[32], rer[32], rad[32];
#pragma unroll
    for (int i = 0; i < 32; ++i) {
        int k = 32 * q + i;
        rw1a[i] = ldw<BF16>(vu_w1, (size_t)k * DD + d);
        rw1b[i] = ldw<BF16>(vu_w1, (size_t)(DD + k) * DD + d);
        rw2[i]  = ldw<BF16>(vu_w2, (size_t)k * DD + d);
        rer[i]  = ldw<BF16>(er_w,  (size_t)k * DD + d);
        rad[i]  = ldw<BF16>(ad_w,  (size_t)k * DD + d);
    }
    const float b1r = ldw<BF16>(vu_b1, d);
    const float b2r = ldw<BF16>(vu_b2, d);
    const float ebr = ldw<BF16>(er_b, d);
    const float abr = ldw<BF16>(ad_b, d);

    __syncthreads();   // key_w / qrow ready

    // ================= PRECOMPUTE: softmax rows + qe-projections =================
    for (int ii = 0; ii < 13; ++ii) {
        const int nrows = (ii == 12) ? 4 : 8;
        // load qe8 rows (packed bf16; one u32 word per thread)
        {
            int r = t >> 6, w = t & 63;
            if (r < nrows) {
                int row = sm.qrow[8 * ii + r];
                if (BF16) {
                    sm.u.pre.qe8[r][w] = ((const unsigned int*)emb)[((size_t)row << 6) + w];
                } else {
                    const float* ef = (const float*)emb + (((size_t)row) << 7) + 2 * w;
                    sm.u.pre.qe8[r][w] = packbf(ef[0], ef[1]);
                }
            }
        }
        __syncthreads();

        // logits + softmax: wave wv handles s = 8*ii + wv (full dot per lane m = l)
        if (wv < nrows) {
            int m = l;
            int mc = (m < MM) ? m : (MM - 1);
            float a0 = 0.f, a1 = 0.f, a2 = 0.f, a3 = 0.f;
#pragma unroll
            for (int j = 0; j < 32; ++j) {
                uint2 kw = *(const uint2*)&sm.u.pre.key_w[mc * KROW + 2 * j];
                uint2 qw = *(const uint2*)&sm.u.pre.qe8[wv][2 * j];
                a0 = fmaf(bfu_lo(kw.x), bfu_lo(qw.x), a0);
                a1 = fmaf(bfu_hi(kw.x), bfu_hi(qw.x), a1);
                a2 = fmaf(bfu_lo(kw.y), bfu_lo(qw.y), a2);
                a3 = fmaf(bfu_hi(kw.y), bfu_hi(qw.y), a3);
            }
            float lg = (a0 + a1) + (a2 + a3);
            if (m >= MM) lg = -1e30f;
            float mx = lg;
#pragma unroll
            for (int o = 32; o > 0; o >>= 1) mx = fmaxf(mx, __shfl_xor(mx, o));
            float p = (m < MM) ? __expf(lg - mx) : 0.f;
            float sum = p;
#pragma unroll
            for (int o = 32; o > 0; o >>= 1) sum += __shfl_xor(sum, o);
            p = p / sum;                       // zeros for m in [50,64)
            float pn = __shfl_xor(p, 1);       // partner weight
            if ((m & 1) == 0)
                sm.wrow_p[8 * ii + wv][m >> 1] = packbf(p, pn);
        }

        // qe-projection: thread (d,q), k in [32q, 32q+32)
        for (int sr = 0; sr < nrows; ++sr) {
            float p0 = 0.f, p1 = 0.f;
#pragma unroll
            for (int i = 0; i < 16; ++i) {
                unsigned int uw = sm.u.pre.qe8[sr][16 * q + i];
                p0 = fmaf(rw1b[2 * i],     bfu_lo(uw), p0);
                p1 = fmaf(rw1b[2 * i + 1], bfu_hi(uw), p1);
            }
            float qpv = p0 + p1;
            qpv += __shfl_xor(qpv, 16);
            qpv += __shfl_xor(qpv, 32);
            if (q == 0) sm.qp_all[8 * ii + sr][d] = f2bf_bits(qpv);
        }
        __syncthreads();   // before next qe8 overwrite
    }

    // save last qe (s=99 lives in qe8[3]); init xread = 0 (v0=0 -> read0=0); load wrow[0]
    if (t < 64) {
        unsigned int uw = sm.u.pre.qe8[3][t];
        sm.qlast[2 * t]     = bfu_lo(uw);
        sm.qlast[2 * t + 1] = bfu_hi(uw);
    }
    float v[16];
#pragma unroll
    for (int j = 0; j < 16; ++j) v[j] = 0.f;
    float wrowr[16];
    {
        const uint4* wp = (const uint4*)&sm.wrow_p[0][8 * q];
        uint4 w0 = wp[0], w1 = wp[1];
        unsigned int ww[8] = { w0.x, w0.y, w0.z, w0.w, w1.x, w1.y, w1.z, w1.w };
#pragma unroll
        for (int i = 0; i < 8; ++i) { wrowr[2 * i] = bfu_lo(ww[i]); wrowr[2 * i + 1] = bfu_hi(ww[i]); }
    }
    if (q == 0) sm.u.run.xread[XW(d)] = 0.f;
    __syncthreads();

    // ================= SCAN: 3 barriers per step =================
    for (int s = 0; s < SS; ++s) {
        // ---- E: h = tanh(read @ w1a + qp + b1) ----
        {
            float qpv = bf2f(sm.qp_all[s][d]);
            const float4* xp = (const float4*)&sm.u.run.xread[40 * q];
            float a0 = 0.f, a1 = 0.f, a2 = 0.f, a3 = 0.f;
#pragma unroll
            for (int j = 0; j < 8; ++j) {
                float4 xv = xp[j];
                a0 = fmaf(rw1a[4 * j],     xv.x, a0);
                a1 = fmaf(rw1a[4 * j + 1], xv.y, a1);
                a2 = fmaf(rw1a[4 * j + 2], xv.z, a2);
                a3 = fmaf(rw1a[4 * j + 3], xv.w, a3);
            }
            float acc = (a0 + a1) + (a2 + a3);
            acc += __shfl_xor(acc, 16);
            acc += __shfl_xor(acc, 32);
            float hh = fast_tanh(acc + qpv + b1r);
            if (q == 0) sm.u.run.xh[XW(d)] = hh;
        }
        __syncthreads();

        // ---- F: up = h @ w2 + b2 ----
        {
            const float4* xp = (const float4*)&sm.u.run.xh[40 * q];
            float a0 = 0.f, a1 = 0.f, a2 = 0.f, a3 = 0.f;
#pragma unroll
            for (int j = 0; j < 8; ++j) {
                float4 xv = xp[j];
                a0 = fmaf(rw2[4 * j],     xv.x, a0);
                a1 = fmaf(rw2[4 * j + 1], xv.y, a1);
                a2 = fmaf(rw2[4 * j + 2], xv.z, a2);
                a3 = fmaf(rw2[4 * j + 3], xv.w, a3);
            }
            float acc = (a0 + a1) + (a2 + a3);
            acc += __shfl_xor(acc, 16);
            acc += __shfl_xor(acc, 32);
            float up = acc + b2r;
            if (q == 0) sm.u.run.xup[XW(d)] = up;
        }
        __syncthreads();

        // ---- G: e,a; v-update (w[s]); advance wrow; fused next-read ----
        {
            const float4* xp = (const float4*)&sm.u.run.xup[40 * q];
            float e0 = 0.f, e1 = 0.f, f0 = 0.f, f1 = 0.f;
#pragma unroll
            for (int j = 0; j < 8; ++j) {
                float4 xv = xp[j];
                e0 = fmaf(rer[4 * j],     xv.x, e0); e1 = fmaf(rer[4 * j + 1], xv.y, e1);
                e0 = fmaf(rer[4 * j + 2], xv.z, e0); e1 = fmaf(rer[4 * j + 3], xv.w, e1);
                f0 = fmaf(rad[4 * j],     xv.x, f0); f1 = fmaf(rad[4 * j + 1], xv.y, f1);
                f0 = fmaf(rad[4 * j + 2], xv.z, f0); f1 = fmaf(rad[4 * j + 3], xv.w, f1);
            }
            float ae = e0 + e1, aa = f0 + f1;
            ae += __shfl_xor(ae, 16); ae += __shfl_xor(ae, 32);
            aa += __shfl_xor(aa, 16); aa += __shfl_xor(aa, 32);
            float e = fast_sigmoid(ae + ebr);
            float a = fast_tanh(aa + abr);
#pragma unroll
            for (int j = 0; j < 16; ++j)
                v[j] = fmaf(wrowr[j], fmaf(-e, v[j], a), v[j]);
            if (s + 1 < SS) {   // advance to wrow[s+1]; at s=99 keep wrow[99] for the final read
                const uint4* wp = (const uint4*)&sm.wrow_p[s + 1][8 * q];
                uint4 w0 = wp[0], w1 = wp[1];
                unsigned int ww[8] = { w0.x, w0.y, w0.z, w0.w, w1.x, w1.y, w1.z, w1.w };
#pragma unroll
                for (int i = 0; i < 8; ++i) { wrowr[2 * i] = bfu_lo(ww[i]); wrowr[2 * i + 1] = bfu_hi(ww[i]); }
            }
            float r0 = 0.f, r1 = 0.f;
#pragma unroll
            for (int j = 0; j < 16; j += 2) {
                r0 = fmaf(wrowr[j], v[j], r0);
                r1 = fmaf(wrowr[j + 1], v[j + 1], r1);
            }
            float rr = r0 + r1;
            rr += __shfl_xor(rr, 16);
            rr += __shfl_xor(rr, 32);
            if (q == 0) sm.u.run.xread[XW(d)] = rr;
        }
        __syncthreads();
    }

    // ---- Epilogue: xread holds final read; qlast holds qe[99] ----
    float acc = 0.f;
    if (q < 2) {
#pragma unroll
        for (int sl = 0; sl < 2; ++sl) {
            int sidx = 2 * q + sl;
            const float4* xp = (const float4*)&sm.u.run.xread[40 * sidx];
#pragma unroll
            for (int j = 0; j < 8; ++j) {
                float4 xv = xp[j];
                int k = 32 * sidx + 4 * j;
                acc = fmaf(ldw<BF16>(out_w1, (size_t)k * DD + d),       xv.x, acc);
                acc = fmaf(ldw<BF16>(out_w1, (size_t)(k + 1) * DD + d), xv.y, acc);
                acc = fmaf(ldw<BF16>(out_w1, (size_t)(k + 2) * DD + d), xv.z, acc);
                acc = fmaf(ldw<BF16>(out_w1, (size_t)(k + 3) * DD + d), xv.w, acc);
            }
        }
    } else {
        int half = q - 2;
        const float4* qp4 = (const float4*)&sm.qlast[64 * half];
#pragma unroll
        for (int j = 0; j < 16; ++j) {
            float4 xv = qp4[j];
            int k = DD + 64 * half + 4 * j;
            acc = fmaf(ldw<BF16>(out_w1, (size_t)k * DD + d),       xv.x, acc);
            acc = fmaf(ldw<BF16>(out_w1, (size_t)(k + 1) * DD + d), xv.y, acc);
            acc = fmaf(ldw<BF16>(out_w1, (size_t)(k + 2) * DD + d), xv.z, acc);
            acc = fmaf(ldw<BF16>(out_w1, (size_t)(k + 3) * DD + d), xv.w, acc);
        }
    }
    acc += __shfl_xor(acc, 16);
    acc += __shfl_xor(acc, 32);
    float h1 = fmaxf(acc + ldw<BF16>(out_b1, d), 0.f);
    if (q == 0) sm.u.run.h1f[d] = h1;
    __syncthreads();

    if (t < 64) {
        float xs = fmaf(sm.u.run.h1f[t], ldw<BF16>(out_w2, t),
                        sm.u.run.h1f[64 + t] * ldw<BF16>(out_w2, 64 + t));
#pragma unroll
        for (int o = 32; o > 0; o >>= 1) xs += __shfl_xor(xs, o);
        if (t == 0) {
            float pred = fast_sigmoid(xs + ldw<BF16>(out_b2, 0));
            if (BF16) ((unsigned short*)outp)[b] = f2bf_bits(pred);
            else      ((float*)outp)[b] = pred;
        }
    }
}

__global__ __launch_bounds__(512) void DKVMN_78546361909953_kernel(
    const int* __restrict__ qseq,
    const void* emb, const void* key,
    const void* vu_w1, const void* vu_b1, const void* vu_w2, const void* vu_b2,
    const void* er_w, const void* er_b, const void* ad_w, const void* ad_b,
    const void* out_w1, const void* out_b1, const void* out_w2, const void* out_b2,
    void* outp)
{
    __shared__ SmemT sm;

    // Runtime storage-dtype detection (proven in rounds 5/6: BF16 path taken).
    const unsigned int* eu = (const unsigned int*)emb;
    int cnt = 0;
    for (int i = 0; i < 32; ++i) {
        unsigned int e8 = (eu[i] >> 7) & 0xFFu;
        cnt += (e8 >= 100u && e8 <= 127u) ? 1 : 0;
    }
    if (cnt >= 16)
        dkvmn_impl<true>(qseq, emb, key, vu_w1, vu_b1, vu_w2, vu_b2,
                         er_w, er_b, ad_w, ad_b, out_w1, out_b1, out_w2, out_b2, outp, sm);
    else
        dkvmn_impl<false>(qseq, emb, key, vu_w1, vu_b1, vu_w2, vu_b2,
                          er_w, er_b, ad_w, ad_b, out_w1, out_b1, out_w2, out_b2, outp, sm);
}

extern "C" void kernel_launch(void* const* d_in, const int* in_sizes, int n_in,
                              void* d_out, int out_size, void* d_ws, size_t ws_size,
                              hipStream_t stream) {
    const int* qseq = (const int*)d_in[0];
    // d_in[1] = answer_seq: unused by the reference
    DKVMN_78546361909953_kernel<<<BB, 512, 0, stream>>>(
        qseq,
        d_in[2], d_in[3], d_in[4], d_in[5], d_in[6], d_in[7],
        d_in[8], d_in[9], d_in[10], d_in[11],
        d_in[12], d_in[13], d_in[14], d_in[15],
        d_out);
}